// Round 7
// baseline (311.308 us; speedup 1.0000x reference)
//
#include <hip/hip_runtime.h>
#include <hip/hip_bf16.h>

typedef __bf16 bf16_t;
typedef __attribute__((ext_vector_type(8))) __bf16 bf16x8;
typedef __attribute__((ext_vector_type(4))) __bf16 bf16x4;
typedef __attribute__((ext_vector_type(4))) float floatx4;

#define NB 8192   // rows of x (B)
#define NC 8192   // rows of y (C)
#define ND 256    // feature dim D
#define BM 128
#define BN 128
#define BK 64     // 4 K-iters: best measured config (round 2)
#define LOG2E 1.44269504088896340736f

typedef __attribute__((address_space(3))) void lds_void_t;
typedef __attribute__((address_space(1))) void gl_void_t;

// ---------------------------------------------------------------------------
// prep: fp32 -> bf16 copies of x and y, plus SCALED row squared-norms:
//   x2s[r] = gamma * log2(e) * ||x_r||^2   (same for y2s)
// One wave per row (256 floats = 64 lanes x float4).
// ---------------------------------------------------------------------------
__global__ __launch_bounds__(256) void prep_kernel(
    const float* __restrict__ x, const float* __restrict__ y,
    const float* __restrict__ gamma_p,
    bf16_t* __restrict__ xb, bf16_t* __restrict__ yb,
    float* __restrict__ x2s, float* __restrict__ y2s)
{
    int t    = threadIdx.x;
    int wave = t >> 6;
    int lane = t & 63;
    int row  = blockIdx.x * 4 + wave;   // 0..16383 (x rows then y rows)

    const float* src;
    bf16_t* dst;
    float* nrm;
    int r;
    if (row < NB) { src = x; dst = xb; nrm = x2s; r = row; }
    else          { src = y; dst = yb; nrm = y2s; r = row - NB; }

    float4 v = ((const float4*)(src + (size_t)r * ND))[lane];
    float ss = v.x * v.x + v.y * v.y + v.z * v.z + v.w * v.w;

    bf16x4 o;
    o.x = (__bf16)v.x; o.y = (__bf16)v.y; o.z = (__bf16)v.z; o.w = (__bf16)v.w;
    ((bf16x4*)(dst + (size_t)r * ND))[lane] = o;

    #pragma unroll
    for (int off = 32; off >= 1; off >>= 1)
        ss += __shfl_xor(ss, off, 64);
    if (lane == 0) nrm[r] = ss * (LOG2E * gamma_p[0]);
}

// ---------------------------------------------------------------------------
// RBF GEMM: out[b,c] = 2^( min( A2*dot(x_b,y_c) - (x2s[b]+y2s[c]), 0 ) ).
// EXACT round-2 structure (best measured, 291 us total / gemm ~67 us):
// 128x128 tile, BK=64 single-buffered (4 K-iters), 256 threads (4 waves 2x2),
// wave = 64x64 subtile = 4x4 MFMA 16x16x32 bf16. global_load_lds width=16
// with XOR-swizzled source column (linear LDS dest, rule #21), same XOR on
// the ds_read side -> <=2-way banks. __launch_bounds__(256,3): no spill,
// 3 blocks/CU so epilogues overlap neighbors' K-loops.
// ONE new lever vs round 2: NON-TEMPORAL scalar stores. The 268-MB output
// stream write-allocating in L2 evicts the 8-MB xb/yb panels that all 4096
// blocks re-read 64x; nt keeps panels L2-resident for the staging loads.
// ---------------------------------------------------------------------------
__global__ __launch_bounds__(256, 3) void rbf_gemm_kernel(
    const bf16_t* __restrict__ xb, const bf16_t* __restrict__ yb,
    const float* __restrict__ x2s, const float* __restrict__ y2s,
    const float* __restrict__ gamma_p, float* __restrict__ out)
{
    __shared__ bf16_t lA[BM * BK];   // 16 KB, swizzled row-major 128x64
    __shared__ bf16_t lB[BN * BK];   // 16 KB

    const int t    = threadIdx.x;
    const int lane = t & 63;
    const int wave = t >> 6;
    const int wm   = wave >> 1;      // 0..1 : wave row in 2x2 wave grid
    const int wn   = wave & 1;       // 0..1
    const int quad = lane >> 4;      // 0..3
    const int l15  = lane & 15;

    const int bm = blockIdx.x * BM;  // x-row base
    const int bn = blockIdx.y * BN;  // y-row (output col) base

    const float A2 = 2.0f * LOG2E * gamma_p[0];

    floatx4 acc[4][4];
    #pragma unroll
    for (int i = 0; i < 4; ++i)
        #pragma unroll
        for (int j = 0; j < 4; ++j)
            acc[i][j] = (floatx4){0.f, 0.f, 0.f, 0.f};

    // Staging geometry: 16 KB tile = 1024 chunks of 16 B; thread t, call c
    // owns chunk li = c*256+t -> row = li>>3, k-byte = (li&7)*16.
    // Global row stride: ND*2 = 512 B; k-tile step: BK*2 = 128 B.
    // Source column is XOR-swizzled so linear LDS holds the swizzled layout.
    const char* gA = (const char*)xb + (size_t)bm * (ND * 2);
    const char* gB = (const char*)yb + (size_t)bn * (ND * 2);

    for (int kt = 0; kt < ND / BK; ++kt) {          // 4 iterations
        __syncthreads();   // previous iteration's reads done before overwrite
        #pragma unroll
        for (int c = 0; c < 4; ++c) {
            const int li  = c * 256 + t;
            const int row = li >> 3;                 // 0..127
            const int kb  = (li & 7) * 16;           // 0..112
            const int kbs = kb ^ ((row & 7) << 4);   // swizzled source column
            const size_t goff = (size_t)row * (ND * 2) + kt * (BK * 2) + kbs;
            __builtin_amdgcn_global_load_lds(
                (gl_void_t*)(gA + goff),
                (lds_void_t*)((char*)lA + (size_t)li * 16), 16, 0, 0);
            __builtin_amdgcn_global_load_lds(
                (gl_void_t*)(gB + goff),
                (lds_void_t*)((char*)lB + (size_t)li * 16), 16, 0, 0);
        }
        __syncthreads();   // compiler emits s_waitcnt vmcnt(0) before barrier

        #pragma unroll
        for (int kk = 0; kk < 2; ++kk) {             // two K=32 sub-steps
            bf16x8 af[4], bfr[4];
            const int swz = ((l15 & 7) << 4);        // row&7 == l15&7 here
            const int off = (kk * 64 + quad * 16) ^ swz;
            #pragma unroll
            for (int i = 0; i < 4; ++i) {
                const int ar = wm * 64 + i * 16 + l15;
                af[i]  = *(const bf16x8*)((const char*)lA + ar * (BK * 2) + off);
                const int br = wn * 64 + i * 16 + l15;
                bfr[i] = *(const bf16x8*)((const char*)lB + br * (BK * 2) + off);
            }
            #pragma unroll
            for (int i = 0; i < 4; ++i)
                #pragma unroll
                for (int j = 0; j < 4; ++j)
                    acc[i][j] = __builtin_amdgcn_mfma_f32_16x16x32_bf16(
                        af[i], bfr[j], acc[i][j], 0, 0, 0);
        }
    }

    // Epilogue. C/D layout: col = lane&15, row = quad*4 + reg  [m89/m91].
    // out = 2^( min( A2*dot - (x2s+y2s), 0 ) ) — exact match to
    // exp(-gamma*max(x2+y2-2dot,0)) for gamma >= 0.  Stores are nt.
    #pragma unroll
    for (int i = 0; i < 4; ++i) {
        const int grow0 = bm + wm * 64 + i * 16 + quad * 4;
        float xn[4];
        #pragma unroll
        for (int r = 0; r < 4; ++r) xn[r] = x2s[grow0 + r];
        #pragma unroll
        for (int j = 0; j < 4; ++j) {
            const int gcol = bn + wn * 64 + j * 16 + l15;
            const float yn = y2s[gcol];
            #pragma unroll
            for (int r = 0; r < 4; ++r) {
                float t2 = fmaf(A2, acc[i][j][r], -(xn[r] + yn));
                t2 = fminf(t2, 0.0f);
                __builtin_nontemporal_store(
                    exp2f(t2), out + (size_t)(grow0 + r) * NC + gcol);
            }
        }
    }
}

extern "C" void kernel_launch(void* const* d_in, const int* in_sizes, int n_in,
                              void* d_out, int out_size, void* d_ws, size_t ws_size,
                              hipStream_t stream) {
    const float* x = (const float*)d_in[0];
    const float* y = (const float*)d_in[1];
    const float* gamma = (const float*)d_in[2];
    float* out = (float*)d_out;

    // Workspace layout: xb (4 MB) | yb (4 MB) | x2s (32 KB) | y2s (32 KB)
    bf16_t* xb = (bf16_t*)d_ws;
    bf16_t* yb = xb + (size_t)NB * ND;
    float*  x2s = (float*)(yb + (size_t)NC * ND);
    float*  y2s = x2s + NB;

    prep_kernel<<<dim3((NB + NC) / 4), dim3(256), 0, stream>>>(
        x, y, gamma, xb, yb, x2s, y2s);
    rbf_gemm_kernel<<<dim3(NB / BM, NC / BN), dim3(256), 0, stream>>>(
        xb, yb, x2s, y2s, gamma, out);
}

// Round 8
// 287.847 us; speedup vs baseline: 1.0815x; 1.0815x over previous
//
#include <hip/hip_runtime.h>
#include <hip/hip_bf16.h>

typedef __bf16 bf16_t;
typedef __attribute__((ext_vector_type(8))) __bf16 bf16x8;
typedef __attribute__((ext_vector_type(4))) __bf16 bf16x4;
typedef __attribute__((ext_vector_type(4))) float floatx4;

#define NB 8192   // rows of x (B)
#define NC 8192   // rows of y (C)
#define ND 256    // feature dim D
#define BM 128
#define BN 128
#define BK 64     // 4 K-iters: best measured config (round 2, 291.0 us)
#define LOG2E 1.44269504088896340736f

typedef __attribute__((address_space(3))) void lds_void_t;
typedef __attribute__((address_space(1))) void gl_void_t;

// ---------------------------------------------------------------------------
// prep: fp32 -> bf16 copies of x and y, plus SCALED row squared-norms:
//   x2s[r] = gamma * log2(e) * ||x_r||^2   (same for y2s)
// One wave per row (256 floats = 64 lanes x float4).
// ---------------------------------------------------------------------------
__global__ __launch_bounds__(256) void prep_kernel(
    const float* __restrict__ x, const float* __restrict__ y,
    const float* __restrict__ gamma_p,
    bf16_t* __restrict__ xb, bf16_t* __restrict__ yb,
    float* __restrict__ x2s, float* __restrict__ y2s)
{
    int t    = threadIdx.x;
    int wave = t >> 6;
    int lane = t & 63;
    int row  = blockIdx.x * 4 + wave;   // 0..16383 (x rows then y rows)

    const float* src;
    bf16_t* dst;
    float* nrm;
    int r;
    if (row < NB) { src = x; dst = xb; nrm = x2s; r = row; }
    else          { src = y; dst = yb; nrm = y2s; r = row - NB; }

    float4 v = ((const float4*)(src + (size_t)r * ND))[lane];
    float ss = v.x * v.x + v.y * v.y + v.z * v.z + v.w * v.w;

    bf16x4 o;
    o.x = (__bf16)v.x; o.y = (__bf16)v.y; o.z = (__bf16)v.z; o.w = (__bf16)v.w;
    ((bf16x4*)(dst + (size_t)r * ND))[lane] = o;

    #pragma unroll
    for (int off = 32; off >= 1; off >>= 1)
        ss += __shfl_xor(ss, off, 64);
    if (lane == 0) nrm[r] = ss * (LOG2E * gamma_p[0]);
}

// ---------------------------------------------------------------------------
// RBF GEMM: out[b,c] = 2^( min( A2*dot(x_b,y_c) - (x2s[b]+y2s[c]), 0 ) ).
// EXACT round-2 structure — best measured configuration of the session
// (291.0 us total; fill-adjusted gemm ~67 us vs ~55-60 us store-BW floor):
// 128x128 tile, BK=64 single-buffered (4 K-iters), 256 threads (4 waves 2x2),
// wave = 64x64 subtile = 4x4 MFMA 16x16x32 bf16. global_load_lds width=16
// with XOR-swizzled source column (linear LDS dest, rule #21), same XOR on
// the ds_read side -> <=2-way banks. __launch_bounds__(256,3): no spill,
// 3 blocks/CU so epilogues overlap neighbors' K-loops.
// Measured-dead-end levers (do NOT re-add): (256,4) VGPR cap -> spill +34%;
// BK=32 dbuf prefetch -> +12 us (barrier-drain doubles); LDS-transpose
// epilogue + float4 nt -> +8 us; LDS-free L2-direct frags -> 2.5x (latency-
// bound, MfmaUtil 7.9%); nt scalar stores -> +20 us (breaks L2 write
// coalescing); XCD swizzles -> neutral (inputs L2/L3-resident, FETCH~15 MB).
// ---------------------------------------------------------------------------
__global__ __launch_bounds__(256, 3) void rbf_gemm_kernel(
    const bf16_t* __restrict__ xb, const bf16_t* __restrict__ yb,
    const float* __restrict__ x2s, const float* __restrict__ y2s,
    const float* __restrict__ gamma_p, float* __restrict__ out)
{
    __shared__ bf16_t lA[BM * BK];   // 16 KB, swizzled row-major 128x64
    __shared__ bf16_t lB[BN * BK];   // 16 KB

    const int t    = threadIdx.x;
    const int lane = t & 63;
    const int wave = t >> 6;
    const int wm   = wave >> 1;      // 0..1 : wave row in 2x2 wave grid
    const int wn   = wave & 1;       // 0..1
    const int quad = lane >> 4;      // 0..3
    const int l15  = lane & 15;

    const int bm = blockIdx.x * BM;  // x-row base
    const int bn = blockIdx.y * BN;  // y-row (output col) base

    const float A2 = 2.0f * LOG2E * gamma_p[0];

    floatx4 acc[4][4];
    #pragma unroll
    for (int i = 0; i < 4; ++i)
        #pragma unroll
        for (int j = 0; j < 4; ++j)
            acc[i][j] = (floatx4){0.f, 0.f, 0.f, 0.f};

    // Staging geometry: 16 KB tile = 1024 chunks of 16 B; thread t, call c
    // owns chunk li = c*256+t -> row = li>>3, k-byte = (li&7)*16.
    // Global row stride: ND*2 = 512 B; k-tile step: BK*2 = 128 B.
    // Source column is XOR-swizzled so linear LDS holds the swizzled layout.
    const char* gA = (const char*)xb + (size_t)bm * (ND * 2);
    const char* gB = (const char*)yb + (size_t)bn * (ND * 2);

    for (int kt = 0; kt < ND / BK; ++kt) {          // 4 iterations
        __syncthreads();   // previous iteration's reads done before overwrite
        #pragma unroll
        for (int c = 0; c < 4; ++c) {
            const int li  = c * 256 + t;
            const int row = li >> 3;                 // 0..127
            const int kb  = (li & 7) * 16;           // 0..112
            const int kbs = kb ^ ((row & 7) << 4);   // swizzled source column
            const size_t goff = (size_t)row * (ND * 2) + kt * (BK * 2) + kbs;
            __builtin_amdgcn_global_load_lds(
                (gl_void_t*)(gA + goff),
                (lds_void_t*)((char*)lA + (size_t)li * 16), 16, 0, 0);
            __builtin_amdgcn_global_load_lds(
                (gl_void_t*)(gB + goff),
                (lds_void_t*)((char*)lB + (size_t)li * 16), 16, 0, 0);
        }
        __syncthreads();   // compiler emits s_waitcnt vmcnt(0) before barrier

        #pragma unroll
        for (int kk = 0; kk < 2; ++kk) {             // two K=32 sub-steps
            bf16x8 af[4], bfr[4];
            const int swz = ((l15 & 7) << 4);        // row&7 == l15&7 here
            const int off = (kk * 64 + quad * 16) ^ swz;
            #pragma unroll
            for (int i = 0; i < 4; ++i) {
                const int ar = wm * 64 + i * 16 + l15;
                af[i]  = *(const bf16x8*)((const char*)lA + ar * (BK * 2) + off);
                const int br = wn * 64 + i * 16 + l15;
                bfr[i] = *(const bf16x8*)((const char*)lB + br * (BK * 2) + off);
            }
            #pragma unroll
            for (int i = 0; i < 4; ++i)
                #pragma unroll
                for (int j = 0; j < 4; ++j)
                    acc[i][j] = __builtin_amdgcn_mfma_f32_16x16x32_bf16(
                        af[i], bfr[j], acc[i][j], 0, 0, 0);
        }
    }

    // Epilogue. C/D layout: col = lane&15, row = quad*4 + reg  [m89/m91].
    // out = 2^( min( A2*dot - (x2s+y2s), 0 ) ) — exact match to
    // exp(-gamma*max(x2+y2-2dot,0)) for gamma >= 0.
    #pragma unroll
    for (int i = 0; i < 4; ++i) {
        const int grow0 = bm + wm * 64 + i * 16 + quad * 4;
        float xn[4];
        #pragma unroll
        for (int r = 0; r < 4; ++r) xn[r] = x2s[grow0 + r];
        #pragma unroll
        for (int j = 0; j < 4; ++j) {
            const int gcol = bn + wn * 64 + j * 16 + l15;
            const float yn = y2s[gcol];
            #pragma unroll
            for (int r = 0; r < 4; ++r) {
                float t2 = fmaf(A2, acc[i][j][r], -(xn[r] + yn));
                t2 = fminf(t2, 0.0f);
                out[(size_t)(grow0 + r) * NC + gcol] = exp2f(t2);
            }
        }
    }
}

extern "C" void kernel_launch(void* const* d_in, const int* in_sizes, int n_in,
                              void* d_out, int out_size, void* d_ws, size_t ws_size,
                              hipStream_t stream) {
    const float* x = (const float*)d_in[0];
    const float* y = (const float*)d_in[1];
    const float* gamma = (const float*)d_in[2];
    float* out = (float*)d_out;

    // Workspace layout: xb (4 MB) | yb (4 MB) | x2s (32 KB) | y2s (32 KB)
    bf16_t* xb = (bf16_t*)d_ws;
    bf16_t* yb = xb + (size_t)NB * ND;
    float*  x2s = (float*)(yb + (size_t)NC * ND);
    float*  y2s = x2s + NB;

    prep_kernel<<<dim3((NB + NC) / 4), dim3(256), 0, stream>>>(
        x, y, gamma, xb, yb, x2s, y2s);
    rbf_gemm_kernel<<<dim3(NB / BM, NC / BN), dim3(256), 0, stream>>>(
        xb, yb, x2s, y2s, gamma, out);
}